// Round 3
// baseline (804.447 us; speedup 1.0000x reference)
//
#include <hip/hip_runtime.h>
#include <math.h>

typedef float f32x4 __attribute__((ext_vector_type(4)));

#define BN_EPS 1e-5f

// ---------------------------------------------------------------------------
// K1: fused MLP 3->64->128 (BN+ReLU each), writes h2 NATURAL layout: h2[b][n][c]
// grid 128 blocks x 256 thr; block = (b, 64-point chunk)
// ---------------------------------------------------------------------------
__global__ __launch_bounds__(256) void k1_mlp(
    const float* __restrict__ x,
    const float* __restrict__ w1, const float* __restrict__ g1,
    const float* __restrict__ b1, const float* __restrict__ m1,
    const float* __restrict__ v1,
    const float* __restrict__ w2, const float* __restrict__ g2,
    const float* __restrict__ b2, const float* __restrict__ m2,
    const float* __restrict__ v2,
    float* __restrict__ h2)
{
  __shared__ float w1s[64 * 3];
  __shared__ float s1c[64], o1c[64];
  __shared__ float w2s[64 * 132];   // [o][j], padded stride 132
  __shared__ float s2c[128], o2c[128];
  __shared__ float h1s[64 * 64];    // [o][n]

  const int tid = threadIdx.x;
  const int b = blockIdx.x >> 5;
  const int n0 = (blockIdx.x & 31) << 6;

  if (tid < 64) {
    float s = g1[tid] / sqrtf(v1[tid] + BN_EPS);
    s1c[tid] = s;
    o1c[tid] = b1[tid] - m1[tid] * s;
    w1s[tid * 3 + 0] = w1[tid * 3 + 0];
    w1s[tid * 3 + 1] = w1[tid * 3 + 1];
    w1s[tid * 3 + 2] = w1[tid * 3 + 2];
  }
  if (tid < 128) {
    float s = g2[tid] / sqrtf(v2[tid] + BN_EPS);
    s2c[tid] = s;
    o2c[tid] = b2[tid] - m2[tid] * s;
  }
  for (int it = 0; it < 32; ++it) {
    int idx = tid + (it << 8);          // 8192
    int o = idx & 63, j = idx >> 6;
    w2s[o * 132 + j] = w2[j * 64 + o];  // transpose in LDS
  }
  __syncthreads();

  const int n = tid & 63, half = tid >> 6;

  // phase 1: h1 for o in [half*16, half*16+16)
  const float* xp = x + ((size_t)(b << 11) + n0 + n) * 3;
  float xv0 = xp[0], xv1 = xp[1], xv2 = xp[2];
  for (int oo = 0; oo < 16; ++oo) {
    int o = (half << 4) + oo;
    float d = xv0 * w1s[o * 3] + xv1 * w1s[o * 3 + 1] + xv2 * w1s[o * 3 + 2];
    d = d * s1c[o] + o1c[o];
    h1s[o * 64 + n] = fmaxf(d, 0.f);
  }
  __syncthreads();

  // phase 2: j in [half*32, half*32+32)
  float acc[32];
  #pragma unroll
  for (int jj = 0; jj < 32; ++jj) acc[jj] = 0.f;
  const int j0 = half << 5;
  for (int o = 0; o < 64; ++o) {
    float a = h1s[o * 64 + n];
    const f32x4* wrow = (const f32x4*)&w2s[o * 132 + j0];
    #pragma unroll
    for (int jg = 0; jg < 8; ++jg) {
      f32x4 wv = wrow[jg];
      acc[jg * 4 + 0] = fmaf(a, wv[0], acc[jg * 4 + 0]);
      acc[jg * 4 + 1] = fmaf(a, wv[1], acc[jg * 4 + 1]);
      acc[jg * 4 + 2] = fmaf(a, wv[2], acc[jg * 4 + 2]);
      acc[jg * 4 + 3] = fmaf(a, wv[3], acc[jg * 4 + 3]);
    }
  }
  // write h2[b][n0+n][j0..j0+32]   (natural layout, 128B contiguous/thread)
  float* hrow = h2 + ((size_t)(b << 11) + n0 + n) * 128 + j0;
  #pragma unroll
  for (int jg = 0; jg < 8; ++jg) {
    f32x4 v;
    #pragma unroll
    for (int q = 0; q < 4; ++q) {
      int j = j0 + jg * 4 + q;
      v[q] = fmaxf(acc[jg * 4 + q] * s2c[j] + o2c[j], 0.f);
    }
    *(f32x4*)(hrow + jg * 4) = v;
  }
}

// ---------------------------------------------------------------------------
// K2: feat[b][k][o] = max_n  h2[b,n,:] . wb[k,o,:]
// (BN applied later; positive scale => commutes with max)
//
// Scalar-A formulation: lane <-> output column o (one ds_read_b32 per kk,
// stride-1 => conflict-free); A rows are wave-uniform => SMEM s_load path,
// A never touches LDS. grid 512 = (b,k) x 8 o-tiles of 128; 512 thr (8 waves:
// o-half = w&1, n-quarter = w>>1). LDS 70KB -> 2 blocks/CU -> 4 waves/SIMD.
// ---------------------------------------------------------------------------
__global__ __launch_bounds__(512) void k2_branch_max(
    const float* __restrict__ h2,   // [4][2048][128]
    const float* __restrict__ wb,   // [16][1024][128]
    float* __restrict__ feat)       // [4][16][1024]
{
  __shared__ float Wt[128 * 132];   // [c][o] padded
  __shared__ float redm[4][128];

  const int tid = threadIdx.x;
  const int ot = blockIdx.x & 7;
  const int p = blockIdx.x >> 3;
  const int k = p & 15, b = p >> 4;
  const int o0 = ot << 7;

  // stage Wt[c][ol] = wb[k][o0+ol][c]  (coalesced reads, transpose in LDS)
  {
    const float* wbk = wb + ((size_t)(k << 10) + o0) * 128;
    for (int it = 0; it < 8; ++it) {
      int idx = tid + (it << 9);        // 4096 float4s
      int ol = idx >> 5, cc = (idx & 31) << 2;
      f32x4 v = *(const f32x4*)(wbk + (size_t)ol * 128 + cc);
      Wt[(cc + 0) * 132 + ol] = v[0];
      Wt[(cc + 1) * 132 + ol] = v[1];
      Wt[(cc + 2) * 132 + ol] = v[2];
      Wt[(cc + 3) * 132 + ol] = v[3];
    }
  }
  __syncthreads();

  const int lane = tid & 63;
  const int wu = __builtin_amdgcn_readfirstlane(tid >> 6);  // wave id, uniform
  const int oL = ((wu & 1) << 6) + lane;   // 0..127 (lane-consecutive)
  const int nh = (wu >> 1) << 9;           // n-quarter base: 0/512/1024/1536

  const float* Ab = h2 + ((size_t)(b << 11) + nh) * 128;   // uniform per wave

  float mx = -3.4e38f;
  for (int ch = 0; ch < 64; ++ch) {        // 64 chunks x 8 n
    const float* a0 = Ab + (size_t)(ch << 3) * 128;        // uniform
    float acc[8];
    #pragma unroll
    for (int j = 0; j < 8; ++j) acc[j] = 0.f;
    #pragma unroll 8
    for (int kk = 0; kk < 128; ++kk) {
      float wv = Wt[kk * 132 + oL];        // 256B/wave, 2 lanes/bank: free
      #pragma unroll
      for (int j = 0; j < 8; ++j)
        acc[j] = fmaf(a0[j * 128 + kk], wv, acc[j]);  // A: uniform s_load
    }
    #pragma unroll
    for (int j = 0; j < 8; ++j) mx = fmaxf(mx, acc[j]);
  }

  redm[wu >> 1][oL] = mx;
  __syncthreads();
  if (tid < 128) {
    float m = fmaxf(fmaxf(redm[0][tid], redm[1][tid]),
                    fmaxf(redm[2][tid], redm[3][tid]));
    feat[((size_t)(b * 16 + k) << 10) + o0 + tid] = m;
  }
}

// ---------------------------------------------------------------------------
// K3a: caps[b][i][e] = squash_e( BN(feat[b][e][i]) ),  e=16
// grid 16 x 256
// ---------------------------------------------------------------------------
__global__ __launch_bounds__(256) void k3a_caps(
    const float* __restrict__ feat,
    const float* __restrict__ gb, const float* __restrict__ bb,
    const float* __restrict__ mb, const float* __restrict__ vb,
    float* __restrict__ caps)
{
  int g = blockIdx.x * 256 + threadIdx.x;  // 4096
  int b = g >> 10, i = g & 1023;
  float val[16];
  float ss = 0.f;
  #pragma unroll
  for (int e = 0; e < 16; ++e) {
    int ei = (e << 10) + i;
    float f = feat[((size_t)(b << 4) << 10) + ei];
    float sc = gb[ei] / sqrtf(vb[ei] + BN_EPS);
    float vv = (f - mb[ei]) * sc + bb[ei];
    val[e] = vv;
    ss += vv * vv;
  }
  float nrm = sqrtf(ss);
  float scl = nrm / (1.f + nrm * nrm);
  f32x4* cp = (f32x4*)&caps[(size_t)((b << 10) + i) << 4];
  #pragma unroll
  for (int q = 0; q < 4; ++q) {
    f32x4 v;
    v[0] = val[q * 4 + 0] * scl; v[1] = val[q * 4 + 1] * scl;
    v[2] = val[q * 4 + 2] * scl; v[3] = val[q * 4 + 3] * scl;
    cp[q] = v;
  }
}

// ---------------------------------------------------------------------------
// K3b: u[b][o][i][v] = sum_e caps[b][i][e] * Wc[o][i][e][v]
//      + partial s0 (= sum_i u) per (o, i-tile)
// grid 1024 blocks (o=32 x itile=32), 256 thr
// ---------------------------------------------------------------------------
__global__ __launch_bounds__(256) void k3b_u(
    const float* __restrict__ caps, const float* __restrict__ Wc,
    float* __restrict__ u, float* __restrict__ s0p)
{
  __shared__ float caps_l[4 * 32 * 16];  // [b][il][e]
  __shared__ float s_red[16 * 32];       // [w*4+b][v]

  const int tid = threadIdx.x;
  const int o = blockIdx.x & 31, it = blockIdx.x >> 5;
  const int i0 = it << 5;

  for (int ld = 0; ld < 8; ++ld) {
    int idx = tid + (ld << 8);  // 2048 = b*512 + il*16 + e
    int bq = idx >> 9, il = (idx >> 4) & 31, e = idx & 15;
    caps_l[idx] = caps[(size_t)(((bq << 10) + i0 + il) << 4) + e];
  }
  __syncthreads();

  const int w = tid >> 6, lane = tid & 63;
  const int eh = lane >> 5, v = lane & 31;
  float s0acc[4] = {0.f, 0.f, 0.f, 0.f};

  for (int ii = 0; ii < 8; ++ii) {
    int il = (w << 3) + ii;
    int i = i0 + il;
    const float* wc = Wc + ((size_t)(o << 10) + i) * 512 + (eh << 8) + v;
    float acc[4] = {0.f, 0.f, 0.f, 0.f};
    #pragma unroll
    for (int ee = 0; ee < 8; ++ee) {
      float wv = wc[ee * 32];
      int e = (eh << 3) + ee;
      #pragma unroll
      for (int bq = 0; bq < 4; ++bq)
        acc[bq] = fmaf(caps_l[bq * 512 + il * 16 + e], wv, acc[bq]);
    }
    #pragma unroll
    for (int bq = 0; bq < 4; ++bq) {
      acc[bq] += __shfl_xor(acc[bq], 32);
      if (eh == 0) {
        u[(size_t)((((bq << 5) + o) << 10) + i) * 32 + v] = acc[bq];
        s0acc[bq] += acc[bq];
      }
    }
  }
  if (eh == 0) {
    #pragma unroll
    for (int bq = 0; bq < 4; ++bq) s_red[((w << 2) + bq) * 32 + v] = s0acc[bq];
  }
  __syncthreads();
  if (tid < 128) {
    int bq = tid >> 5, vv = tid & 31;
    float s = s_red[bq * 32 + vv] + s_red[(4 + bq) * 32 + vv] +
              s_red[(8 + bq) * 32 + vv] + s_red[(12 + bq) * 32 + vv];
    s0p[(size_t)(((bq << 5) + it) << 5 | o) * 32 + vv] = s;
  }
}

// ---------------------------------------------------------------------------
// K4: out = squash_v( prescale * sum_it spart[b][it][o][v] )
// grid 4 (b) x 256
// ---------------------------------------------------------------------------
__global__ __launch_bounds__(256) void k4_squash(
    const float* __restrict__ sp, float* __restrict__ out, float prescale)
{
  const int tid = threadIdx.x;
  const int b = blockIdx.x;
  const int o = tid >> 3, vq = (tid & 7) << 2;
  f32x4 acc = {0.f, 0.f, 0.f, 0.f};
  for (int it = 0; it < 32; ++it) {
    f32x4 p = *(const f32x4*)(sp + (size_t)(((b << 5) + it) << 5 | o) * 32 + vq);
    acc += p;
  }
  acc *= prescale;
  float ss = acc[0] * acc[0] + acc[1] * acc[1] + acc[2] * acc[2] + acc[3] * acc[3];
  ss += __shfl_xor(ss, 1);
  ss += __shfl_xor(ss, 2);
  ss += __shfl_xor(ss, 4);
  float nrm = sqrtf(ss);
  float scl = nrm / (1.f + nrm * nrm);
  f32x4 r = acc * scl;
  *(f32x4*)(out + (size_t)((b << 5) + o) * 32 + vq) = r;
}

// ---------------------------------------------------------------------------
// K5: one routing pass over u.
// pass 0: bl = agree(a0,u);          store bl -> bout; c=softmax_o(bl); s1 += c*u
// pass 1: bl = bprev + agree(a1,u);                    c=softmax_o(bl); s2 += c*u
// grid 128 blocks (b=4 x itile=32), 256 thr; wave handles 8 i's.
// ---------------------------------------------------------------------------
__global__ __launch_bounds__(256) void k5_route(
    const float* __restrict__ u, const float* __restrict__ aprev,
    const float* __restrict__ bprev, float* __restrict__ bout,
    float* __restrict__ spart, int pass)
{
  __shared__ float a_l[32 * 33];
  __shared__ float u_l[4 * 32 * 33];
  __shared__ float s_red[4 * 32 * 33];

  const int tid = threadIdx.x;
  const int b = blockIdx.x >> 5, it = blockIdx.x & 31;
  const int i0 = it << 5;

  for (int ld = 0; ld < 4; ++ld) {
    int idx = tid + (ld << 8);  // 1024
    int o = idx >> 5, v = idx & 31;
    a_l[o * 33 + v] = aprev[((b << 5) + o) * 32 + v];
  }
  __syncthreads();

  const int w = tid >> 6, lane = tid & 63;
  const int ln5 = lane & 31, hb = lane >> 5;
  float* uw = &u_l[w * 1056];

  float sacc[16];
  #pragma unroll
  for (int q = 0; q < 16; ++q) sacc[q] = 0.f;

  for (int ii = 0; ii < 8; ++ii) {
    int i = i0 + (w << 3) + ii;
    // stage u block [32 o][32 v] (wave-local; compiler inserts lgkm waits)
    #pragma unroll
    for (int rr = 0; rr < 16; ++rr) {
      int o = (rr << 1) + hb;
      uw[o * 33 + ln5] = u[(size_t)((((b << 5) + o) << 10) + i) * 32 + ln5];
    }
    // agree[o]: lane (ln5=o, hb=v-half)
    float ag = 0.f;
    #pragma unroll
    for (int q = 0; q < 16; ++q) {
      int vv = (hb << 4) + q;
      ag = fmaf(a_l[ln5 * 33 + vv], uw[ln5 * 33 + vv], ag);
    }
    ag += __shfl_xor(ag, 32);
    float bl = ag;
    if (pass == 1) bl += bprev[(((b << 5) + ln5) << 10) + i];
    if (pass == 0 && hb == 0) bout[(((b << 5) + ln5) << 10) + i] = bl;
    // softmax over o (32 values, one per lane within each half)
    float m = bl;
    m = fmaxf(m, __shfl_xor(m, 1));
    m = fmaxf(m, __shfl_xor(m, 2));
    m = fmaxf(m, __shfl_xor(m, 4));
    m = fmaxf(m, __shfl_xor(m, 8));
    m = fmaxf(m, __shfl_xor(m, 16));
    float e = expf(bl - m);
    float sm = e;
    sm += __shfl_xor(sm, 1);
    sm += __shfl_xor(sm, 2);
    sm += __shfl_xor(sm, 4);
    sm += __shfl_xor(sm, 8);
    sm += __shfl_xor(sm, 16);
    float c = e / sm;
    #pragma unroll
    for (int q = 0; q < 16; ++q) {
      int vv = (hb << 4) + q;
      sacc[q] = fmaf(c, uw[ln5 * 33 + vv], sacc[q]);
    }
  }
  #pragma unroll
  for (int q = 0; q < 16; ++q)
    s_red[w * 1056 + ln5 * 33 + (hb << 4) + q] = sacc[q];
  __syncthreads();
  for (int ld = 0; ld < 4; ++ld) {
    int idx = tid + (ld << 8);
    int o = idx >> 5, vv = idx & 31;
    float s = s_red[o * 33 + vv] + s_red[1056 + o * 33 + vv] +
              s_red[2112 + o * 33 + vv] + s_red[3168 + o * 33 + vv];
    spart[(size_t)(((b << 5) + it) << 5 | o) * 32 + vv] = s;
  }
}

// ---------------------------------------------------------------------------
extern "C" void kernel_launch(void* const* d_in, const int* in_sizes, int n_in,
                              void* d_out, int out_size, void* d_ws, size_t ws_size,
                              hipStream_t stream) {
  const float* x  = (const float*)d_in[0];
  const float* w1 = (const float*)d_in[1];
  const float* g1 = (const float*)d_in[2];
  const float* b1 = (const float*)d_in[3];
  const float* m1 = (const float*)d_in[4];
  const float* v1 = (const float*)d_in[5];
  const float* w2 = (const float*)d_in[6];
  const float* g2 = (const float*)d_in[7];
  const float* b2 = (const float*)d_in[8];
  const float* m2 = (const float*)d_in[9];
  const float* v2 = (const float*)d_in[10];
  const float* wb = (const float*)d_in[11];
  const float* gb = (const float*)d_in[12];
  const float* bb = (const float*)d_in[13];
  const float* mb = (const float*)d_in[14];
  const float* vb = (const float*)d_in[15];
  const float* Wc = (const float*)d_in[16];
  float* out = (float*)d_out;
  float* ws = (float*)d_ws;

  // workspace layout (floats); everything is fully written before read,
  // so no zero-init needed despite 0xAA poisoning.
  float* h2   = ws + 0;         // 4*2048*128      = 1048576  [b][n][c]
  float* feat = ws + 1048576;   // 4*16*1024       = 65536
  float* caps = ws + 1114112;   // 4*1024*16       = 65536
  float* u    = ws + 1179648;   // 4*32*1024*32    = 4194304
  float* s0p  = ws + 5373952;   // 4*32*32*32      = 131072
  float* s1p  = ws + 5505024;   // 131072
  float* s2p  = ws + 5636096;   // 131072
  float* a0   = ws + 5767168;   // 4096
  float* a1   = ws + 5771264;   // 4096
  float* b1l  = ws + 5775360;   // 4*32*1024       = 131072
  // total 5906432 floats = 23.6 MB

  k1_mlp<<<128, 256, 0, stream>>>(x, w1, g1, b1, m1, v1,
                                  w2, g2, b2, m2, v2, h2);
  k2_branch_max<<<512, 512, 0, stream>>>(h2, wb, feat);
  k3a_caps<<<16, 256, 0, stream>>>(feat, gb, bb, mb, vb, caps);
  k3b_u<<<1024, 256, 0, stream>>>(caps, Wc, u, s0p);
  k4_squash<<<4, 256, 0, stream>>>(s0p, a0, 1.f / 32.f);
  k5_route<<<128, 256, 0, stream>>>(u, a0, b1l, b1l, s1p, 0);
  k4_squash<<<4, 256, 0, stream>>>(s1p, a1, 1.f);
  k5_route<<<128, 256, 0, stream>>>(u, a1, b1l, b1l, s2p, 1);
  k4_squash<<<4, 256, 0, stream>>>(s2p, out, 1.f);
}

// Round 5
// 562.589 us; speedup vs baseline: 1.4299x; 1.4299x over previous
//
#include <hip/hip_runtime.h>
#include <math.h>

typedef float f32x4 __attribute__((ext_vector_type(4)));

#define BN_EPS 1e-5f

// ---------------------------------------------------------------------------
// K1: fused MLP 3->64->128 (BN+ReLU each), writes h2 TRANSPOSED: h2T[b][c][n]
// grid 128 blocks x 256 thr; block = (b, 64-point chunk)
// ---------------------------------------------------------------------------
__global__ __launch_bounds__(256) void k1_mlp(
    const float* __restrict__ x,
    const float* __restrict__ w1, const float* __restrict__ g1,
    const float* __restrict__ b1, const float* __restrict__ m1,
    const float* __restrict__ v1,
    const float* __restrict__ w2, const float* __restrict__ g2,
    const float* __restrict__ b2, const float* __restrict__ m2,
    const float* __restrict__ v2,
    float* __restrict__ h2T)
{
  __shared__ float w1s[64 * 3];
  __shared__ float s1c[64], o1c[64];
  __shared__ float w2s[64 * 132];   // [o][j], padded stride 132
  __shared__ float s2c[128], o2c[128];
  __shared__ float h1s[64 * 64];    // [o][n]

  const int tid = threadIdx.x;
  const int b = blockIdx.x >> 5;
  const int n0 = (blockIdx.x & 31) << 6;

  if (tid < 64) {
    float s = g1[tid] / sqrtf(v1[tid] + BN_EPS);
    s1c[tid] = s;
    o1c[tid] = b1[tid] - m1[tid] * s;
    w1s[tid * 3 + 0] = w1[tid * 3 + 0];
    w1s[tid * 3 + 1] = w1[tid * 3 + 1];
    w1s[tid * 3 + 2] = w1[tid * 3 + 2];
  }
  if (tid < 128) {
    float s = g2[tid] / sqrtf(v2[tid] + BN_EPS);
    s2c[tid] = s;
    o2c[tid] = b2[tid] - m2[tid] * s;
  }
  for (int it = 0; it < 32; ++it) {
    int idx = tid + (it << 8);          // 8192
    int o = idx & 63, j = idx >> 6;
    w2s[o * 132 + j] = w2[j * 64 + o];  // transpose in LDS
  }
  __syncthreads();

  const int n = tid & 63, half = tid >> 6;

  // phase 1: h1 for o in [half*16, half*16+16)
  const float* xp = x + ((size_t)(b << 11) + n0 + n) * 3;
  float xv0 = xp[0], xv1 = xp[1], xv2 = xp[2];
  for (int oo = 0; oo < 16; ++oo) {
    int o = (half << 4) + oo;
    float d = xv0 * w1s[o * 3] + xv1 * w1s[o * 3 + 1] + xv2 * w1s[o * 3 + 2];
    d = d * s1c[o] + o1c[o];
    h1s[o * 64 + n] = fmaxf(d, 0.f);
  }
  __syncthreads();

  // phase 2: j in [half*32, half*32+32)
  float acc[32];
  #pragma unroll
  for (int jj = 0; jj < 32; ++jj) acc[jj] = 0.f;
  const int j0 = half << 5;
  for (int o = 0; o < 64; ++o) {
    float a = h1s[o * 64 + n];
    const f32x4* wrow = (const f32x4*)&w2s[o * 132 + j0];
    #pragma unroll
    for (int jg = 0; jg < 8; ++jg) {
      f32x4 wv = wrow[jg];
      acc[jg * 4 + 0] = fmaf(a, wv[0], acc[jg * 4 + 0]);
      acc[jg * 4 + 1] = fmaf(a, wv[1], acc[jg * 4 + 1]);
      acc[jg * 4 + 2] = fmaf(a, wv[2], acc[jg * 4 + 2]);
      acc[jg * 4 + 3] = fmaf(a, wv[3], acc[jg * 4 + 3]);
    }
  }
  #pragma unroll
  for (int jj = 0; jj < 32; ++jj) {
    int j = j0 + jj;
    float vl = acc[jj] * s2c[j] + o2c[j];
    h2T[((size_t)b * 128 + j) * 2048 + n0 + n] = fmaxf(vl, 0.f);
  }
}

// ---------------------------------------------------------------------------
// K2: feat[b][k][o] = max_n  h2[b,n,:] . wb[k,o,:]
// (BN applied later; positive scale => commutes with max)
//
// Hybrid operand delivery: W-tile (128c x 128o) resident in LDS (0.5 B/FMA on
// the LDS return path), A read straight from global h2T[c][n] (8-lane address
// dedup -> tiny unique L2 traffic). Per-lane 8n x 16o register tile, full
// K=128 accumulate, then max. LDS ~70KB -> 2 blocks/CU -> 2 waves/SIMD.
// grid 512 = (b,k) x 8 o-tiles of 128; 256 thr (4 waves, each owns an
// n-quarter of 512, no inter-wave sync in main loop).
// ---------------------------------------------------------------------------
__global__ __launch_bounds__(256, 2) void k2_branch_max(
    const float* __restrict__ h2T,  // [4][128][2048]
    const float* __restrict__ wb,   // [16][1024][128]
    float* __restrict__ feat)       // [4][16][1024]
{
  __shared__ float Wt[128 * 132];   // [c][o] padded (16B-aligned rows: 528B)
  __shared__ float redm[4][128];

  const int tid = threadIdx.x;
  const int ot = blockIdx.x & 7;
  const int p = blockIdx.x >> 3;
  const int k = p & 15, b = p >> 4;
  const int o0 = ot << 7;

  // stage Wt[c][ol] = wb[k][o0+ol][c]  (coalesced reads, transpose in LDS)
  {
    const float* wbk = wb + ((size_t)(k << 10) + o0) * 128;
    for (int it = 0; it < 16; ++it) {
      int idx = tid + (it << 8);        // 4096 float4s
      int ol = idx >> 5, cc = (idx & 31) << 2;
      f32x4 v = *(const f32x4*)(wbk + (size_t)ol * 128 + cc);
      Wt[(cc + 0) * 132 + ol] = v[0];
      Wt[(cc + 1) * 132 + ol] = v[1];
      Wt[(cc + 2) * 132 + ol] = v[2];
      Wt[(cc + 3) * 132 + ol] = v[3];
    }
  }
  __syncthreads();

  const int lane = tid & 63;
  const int wv4 = __builtin_amdgcn_readfirstlane(tid >> 6); // wave id, uniform
  const int nr = lane >> 3;            // 8 n-groups
  const int oc = lane & 7;             // 8 o-groups (16 o each)

  const float* gA = h2T + (size_t)b * (128 * 2048) + (wv4 << 9) + (nr << 3);
  const float* wp = &Wt[oc << 4];

  float mxv[16];
  #pragma unroll
  for (int j = 0; j < 16; ++j) mxv[j] = -3.4e38f;

  for (int nb = 0; nb < 8; ++nb) {     // 8 n-blocks of 64 per wave
    const float* ap = gA + (nb << 6);
    float acc[8][16];
    #pragma unroll
    for (int m = 0; m < 8; ++m)
      #pragma unroll
      for (int j = 0; j < 16; ++j) acc[m][j] = 0.f;

    #pragma unroll 2
    for (int kk = 0; kk < 128; ++kk) {
      f32x4 a0 = *(const f32x4*)(ap + kk * 2048);
      f32x4 a1 = *(const f32x4*)(ap + kk * 2048 + 4);
      const f32x4* wr = (const f32x4*)(wp + kk * 132);
      f32x4 w0 = wr[0], w1 = wr[1], w2 = wr[2], w3 = wr[3];
      #pragma unroll
      for (int m = 0; m < 8; ++m) {
        float am = (m < 4) ? a0[m] : a1[m - 4];
        #pragma unroll
        for (int q = 0; q < 4; ++q) {
          acc[m][q]      = fmaf(am, w0[q], acc[m][q]);
          acc[m][4 + q]  = fmaf(am, w1[q], acc[m][4 + q]);
          acc[m][8 + q]  = fmaf(am, w2[q], acc[m][8 + q]);
          acc[m][12 + q] = fmaf(am, w3[q], acc[m][12 + q]);
        }
      }
    }
    #pragma unroll
    for (int j = 0; j < 16; ++j) {
      float m01 = fmaxf(fmaxf(acc[0][j], acc[1][j]), fmaxf(acc[2][j], acc[3][j]));
      float m23 = fmaxf(fmaxf(acc[4][j], acc[5][j]), fmaxf(acc[6][j], acc[7][j]));
      mxv[j] = fmaxf(mxv[j], fmaxf(m01, m23));
    }
  }

  // reduce across nr-groups (lane bits 3,4,5)
  #pragma unroll
  for (int j = 0; j < 16; ++j) {
    float m = mxv[j];
    m = fmaxf(m, __shfl_xor(m, 8));
    m = fmaxf(m, __shfl_xor(m, 16));
    m = fmaxf(m, __shfl_xor(m, 32));
    mxv[j] = m;
  }
  if (lane < 8) {
    #pragma unroll
    for (int j = 0; j < 16; ++j) redm[wv4][(lane << 4) + j] = mxv[j];
  }
  __syncthreads();
  if (tid < 128) {
    float m = fmaxf(fmaxf(redm[0][tid], redm[1][tid]),
                    fmaxf(redm[2][tid], redm[3][tid]));
    feat[((size_t)(b * 16 + k) << 10) + o0 + tid] = m;
  }
}

// ---------------------------------------------------------------------------
// K3a: caps[b][i][e] = squash_e( BN(feat[b][e][i]) ),  e=16
// grid 16 x 256
// ---------------------------------------------------------------------------
__global__ __launch_bounds__(256) void k3a_caps(
    const float* __restrict__ feat,
    const float* __restrict__ gb, const float* __restrict__ bb,
    const float* __restrict__ mb, const float* __restrict__ vb,
    float* __restrict__ caps)
{
  int g = blockIdx.x * 256 + threadIdx.x;  // 4096
  int b = g >> 10, i = g & 1023;
  float val[16];
  float ss = 0.f;
  #pragma unroll
  for (int e = 0; e < 16; ++e) {
    int ei = (e << 10) + i;
    float f = feat[((size_t)(b << 4) << 10) + ei];
    float sc = gb[ei] / sqrtf(vb[ei] + BN_EPS);
    float vv = (f - mb[ei]) * sc + bb[ei];
    val[e] = vv;
    ss += vv * vv;
  }
  float nrm = sqrtf(ss);
  float scl = nrm / (1.f + nrm * nrm);
  f32x4* cp = (f32x4*)&caps[(size_t)((b << 10) + i) << 4];
  #pragma unroll
  for (int q = 0; q < 4; ++q) {
    f32x4 v;
    v[0] = val[q * 4 + 0] * scl; v[1] = val[q * 4 + 1] * scl;
    v[2] = val[q * 4 + 2] * scl; v[3] = val[q * 4 + 3] * scl;
    cp[q] = v;
  }
}

// ---------------------------------------------------------------------------
// K3b: u[b][o][i][v] = sum_e caps[b][i][e] * Wc[o][i][e][v]
//      + partial s0 (= sum_i u) per (o, i-tile)
// grid 1024 blocks (o=32 x itile=32), 256 thr
// ---------------------------------------------------------------------------
__global__ __launch_bounds__(256) void k3b_u(
    const float* __restrict__ caps, const float* __restrict__ Wc,
    float* __restrict__ u, float* __restrict__ s0p)
{
  __shared__ float caps_l[4 * 32 * 16];  // [b][il][e]
  __shared__ float s_red[16 * 32];       // [w*4+b][v]

  const int tid = threadIdx.x;
  const int o = blockIdx.x & 31, it = blockIdx.x >> 5;
  const int i0 = it << 5;

  for (int ld = 0; ld < 8; ++ld) {
    int idx = tid + (ld << 8);  // 2048 = b*512 + il*16 + e
    int bq = idx >> 9, il = (idx >> 4) & 31, e = idx & 15;
    caps_l[idx] = caps[(size_t)(((bq << 10) + i0 + il) << 4) + e];
  }
  __syncthreads();

  const int w = tid >> 6, lane = tid & 63;
  const int eh = lane >> 5, v = lane & 31;
  float s0acc[4] = {0.f, 0.f, 0.f, 0.f};

  for (int ii = 0; ii < 8; ++ii) {
    int il = (w << 3) + ii;
    int i = i0 + il;
    const float* wc = Wc + ((size_t)(o << 10) + i) * 512 + (eh << 8) + v;
    float acc[4] = {0.f, 0.f, 0.f, 0.f};
    #pragma unroll
    for (int ee = 0; ee < 8; ++ee) {
      float wv = wc[ee * 32];
      int e = (eh << 3) + ee;
      #pragma unroll
      for (int bq = 0; bq < 4; ++bq)
        acc[bq] = fmaf(caps_l[bq * 512 + il * 16 + e], wv, acc[bq]);
    }
    #pragma unroll
    for (int bq = 0; bq < 4; ++bq) {
      acc[bq] += __shfl_xor(acc[bq], 32);
      if (eh == 0) {
        u[(size_t)((((bq << 5) + o) << 10) + i) * 32 + v] = acc[bq];
        s0acc[bq] += acc[bq];
      }
    }
  }
  if (eh == 0) {
    #pragma unroll
    for (int bq = 0; bq < 4; ++bq) s_red[((w << 2) + bq) * 32 + v] = s0acc[bq];
  }
  __syncthreads();
  if (tid < 128) {
    int bq = tid >> 5, vv = tid & 31;
    float s = s_red[bq * 32 + vv] + s_red[(4 + bq) * 32 + vv] +
              s_red[(8 + bq) * 32 + vv] + s_red[(12 + bq) * 32 + vv];
    s0p[(size_t)(((bq << 5) + it) << 5 | o) * 32 + vv] = s;
  }
}

// ---------------------------------------------------------------------------
// K4: out = squash_v( prescale * sum_it spart[b][it][o][v] )
// grid 4 (b) x 256
// ---------------------------------------------------------------------------
__global__ __launch_bounds__(256) void k4_squash(
    const float* __restrict__ sp, float* __restrict__ out, float prescale)
{
  const int tid = threadIdx.x;
  const int b = blockIdx.x;
  const int o = tid >> 3, vq = (tid & 7) << 2;
  f32x4 acc = {0.f, 0.f, 0.f, 0.f};
  for (int it = 0; it < 32; ++it) {
    f32x4 p = *(const f32x4*)(sp + (size_t)(((b << 5) + it) << 5 | o) * 32 + vq);
    acc += p;
  }
  acc *= prescale;
  float ss = acc[0] * acc[0] + acc[1] * acc[1] + acc[2] * acc[2] + acc[3] * acc[3];
  ss += __shfl_xor(ss, 1);
  ss += __shfl_xor(ss, 2);
  ss += __shfl_xor(ss, 4);
  float nrm = sqrtf(ss);
  float scl = nrm / (1.f + nrm * nrm);
  f32x4 r = acc * scl;
  *(f32x4*)(out + (size_t)((b << 5) + o) * 32 + vq) = r;
}

// ---------------------------------------------------------------------------
// K5: one routing pass over u.
// pass 0: bl = agree(a0,u);          store bl -> bout; c=softmax_o(bl); s1 += c*u
// pass 1: bl = bprev + agree(a1,u);                    c=softmax_o(bl); s2 += c*u
// grid 128 blocks (b=4 x itile=32), 256 thr; wave handles 8 i's.
// ---------------------------------------------------------------------------
__global__ __launch_bounds__(256) void k5_route(
    const float* __restrict__ u, const float* __restrict__ aprev,
    const float* __restrict__ bprev, float* __restrict__ bout,
    float* __restrict__ spart, int pass)
{
  __shared__ float a_l[32 * 33];
  __shared__ float u_l[4 * 32 * 33];
  __shared__ float s_red[4 * 32 * 33];

  const int tid = threadIdx.x;
  const int b = blockIdx.x >> 5, it = blockIdx.x & 31;
  const int i0 = it << 5;

  for (int ld = 0; ld < 4; ++ld) {
    int idx = tid + (ld << 8);  // 1024
    int o = idx >> 5, v = idx & 31;
    a_l[o * 33 + v] = aprev[((b << 5) + o) * 32 + v];
  }
  __syncthreads();

  const int w = tid >> 6, lane = tid & 63;
  const int ln5 = lane & 31, hb = lane >> 5;
  float* uw = &u_l[w * 1056];

  float sacc[16];
  #pragma unroll
  for (int q = 0; q < 16; ++q) sacc[q] = 0.f;

  for (int ii = 0; ii < 8; ++ii) {
    int i = i0 + (w << 3) + ii;
    // stage u block [32 o][32 v] (wave-local; compiler inserts lgkm waits)
    #pragma unroll
    for (int rr = 0; rr < 16; ++rr) {
      int o = (rr << 1) + hb;
      uw[o * 33 + ln5] = u[(size_t)((((b << 5) + o) << 10) + i) * 32 + ln5];
    }
    // agree[o]: lane (ln5=o, hb=v-half)
    float ag = 0.f;
    #pragma unroll
    for (int q = 0; q < 16; ++q) {
      int vv = (hb << 4) + q;
      ag = fmaf(a_l[ln5 * 33 + vv], uw[ln5 * 33 + vv], ag);
    }
    ag += __shfl_xor(ag, 32);
    float bl = ag;
    if (pass == 1) bl += bprev[(((b << 5) + ln5) << 10) + i];
    if (pass == 0 && hb == 0) bout[(((b << 5) + ln5) << 10) + i] = bl;
    // softmax over o (32 values, one per lane within each half)
    float m = bl;
    m = fmaxf(m, __shfl_xor(m, 1));
    m = fmaxf(m, __shfl_xor(m, 2));
    m = fmaxf(m, __shfl_xor(m, 4));
    m = fmaxf(m, __shfl_xor(m, 8));
    m = fmaxf(m, __shfl_xor(m, 16));
    float e = expf(bl - m);
    float sm = e;
    sm += __shfl_xor(sm, 1);
    sm += __shfl_xor(sm, 2);
    sm += __shfl_xor(sm, 4);
    sm += __shfl_xor(sm, 8);
    sm += __shfl_xor(sm, 16);
    float c = e / sm;
    #pragma unroll
    for (int q = 0; q < 16; ++q) {
      int vv = (hb << 4) + q;
      sacc[q] = fmaf(c, uw[ln5 * 33 + vv], sacc[q]);
    }
  }
  #pragma unroll
  for (int q = 0; q < 16; ++q)
    s_red[w * 1056 + ln5 * 33 + (hb << 4) + q] = sacc[q];
  __syncthreads();
  for (int ld = 0; ld < 4; ++ld) {
    int idx = tid + (ld << 8);
    int o = idx >> 5, vv = idx & 31;
    float s = s_red[o * 33 + vv] + s_red[1056 + o * 33 + vv] +
              s_red[2112 + o * 33 + vv] + s_red[3168 + o * 33 + vv];
    spart[(size_t)(((b << 5) + it) << 5 | o) * 32 + vv] = s;
  }
}

// ---------------------------------------------------------------------------
extern "C" void kernel_launch(void* const* d_in, const int* in_sizes, int n_in,
                              void* d_out, int out_size, void* d_ws, size_t ws_size,
                              hipStream_t stream) {
  const float* x  = (const float*)d_in[0];
  const float* w1 = (const float*)d_in[1];
  const float* g1 = (const float*)d_in[2];
  const float* b1 = (const float*)d_in[3];
  const float* m1 = (const float*)d_in[4];
  const float* v1 = (const float*)d_in[5];
  const float* w2 = (const float*)d_in[6];
  const float* g2 = (const float*)d_in[7];
  const float* b2 = (const float*)d_in[8];
  const float* m2 = (const float*)d_in[9];
  const float* v2 = (const float*)d_in[10];
  const float* wb = (const float*)d_in[11];
  const float* gb = (const float*)d_in[12];
  const float* bb = (const float*)d_in[13];
  const float* mb = (const float*)d_in[14];
  const float* vb = (const float*)d_in[15];
  const float* Wc = (const float*)d_in[16];
  float* out = (float*)d_out;
  float* ws = (float*)d_ws;

  // workspace layout (floats); everything is fully written before read,
  // so no zero-init needed despite 0xAA poisoning.
  float* h2T  = ws + 0;         // 4*128*2048      = 1048576  [b][c][n]
  float* feat = ws + 1048576;   // 4*16*1024       = 65536
  float* caps = ws + 1114112;   // 4*1024*16       = 65536
  float* u    = ws + 1179648;   // 4*32*1024*32    = 4194304
  float* s0p  = ws + 5373952;   // 4*32*32*32      = 131072
  float* s1p  = ws + 5505024;   // 131072
  float* s2p  = ws + 5636096;   // 131072
  float* a0   = ws + 5767168;   // 4096
  float* a1   = ws + 5771264;   // 4096
  float* b1l  = ws + 5775360;   // 4*32*1024       = 131072
  // total 5906432 floats = 23.6 MB

  k1_mlp<<<128, 256, 0, stream>>>(x, w1, g1, b1, m1, v1,
                                  w2, g2, b2, m2, v2, h2T);
  k2_branch_max<<<512, 256, 0, stream>>>(h2T, wb, feat);
  k3a_caps<<<16, 256, 0, stream>>>(feat, gb, bb, mb, vb, caps);
  k3b_u<<<1024, 256, 0, stream>>>(caps, Wc, u, s0p);
  k4_squash<<<4, 256, 0, stream>>>(s0p, a0, 1.f / 32.f);
  k5_route<<<128, 256, 0, stream>>>(u, a0, b1l, b1l, s1p, 0);
  k4_squash<<<4, 256, 0, stream>>>(s1p, a1, 1.f);
  k5_route<<<128, 256, 0, stream>>>(u, a1, b1l, b1l, s2p, 1);
  k4_squash<<<4, 256, 0, stream>>>(s2p, out, 1.f);
}

// Round 6
// 392.299 us; speedup vs baseline: 2.0506x; 1.4341x over previous
//
#include <hip/hip_runtime.h>
#include <math.h>

typedef float f32x4 __attribute__((ext_vector_type(4)));
typedef short bf16x8 __attribute__((ext_vector_type(8)));

#define BN_EPS 1e-5f

// RNE bf16 split: returns hi bits, rem = v - float(hi)
__device__ __forceinline__ unsigned short bf16_hi(float v, float& rem) {
  unsigned int u = __float_as_uint(v);
  unsigned int r = u + 0x7FFFu + ((u >> 16) & 1u);
  unsigned short h = (unsigned short)(r >> 16);
  rem = v - __uint_as_float((unsigned int)h << 16);
  return h;
}
__device__ __forceinline__ unsigned short bf16_rne(float v) {
  unsigned int u = __float_as_uint(v);
  unsigned int r = u + 0x7FFFu + ((u >> 16) & 1u);
  return (unsigned short)(r >> 16);
}

// ---------------------------------------------------------------------------
// K0: split wb (f32 [16][1024][128]) into bf16 hi/lo arrays.
// grid 2048 x 256, 4 elems/thread
// ---------------------------------------------------------------------------
__global__ __launch_bounds__(256) void k0_wbsplit(
    const float* __restrict__ wb,
    unsigned short* __restrict__ wbh, unsigned short* __restrict__ wbm)
{
  int i = (blockIdx.x * 256 + threadIdx.x) * 4;
  f32x4 v = *(const f32x4*)(wb + i);
  unsigned short h[4], m[4];
  #pragma unroll
  for (int q = 0; q < 4; ++q) {
    float rem;
    h[q] = bf16_hi(v[q], rem);
    m[q] = bf16_rne(rem);
  }
  typedef unsigned short u16x4 __attribute__((ext_vector_type(4)));
  u16x4 vh = {h[0], h[1], h[2], h[3]};
  u16x4 vm = {m[0], m[1], m[2], m[3]};
  *(u16x4*)(wbh + i) = vh;
  *(u16x4*)(wbm + i) = vm;
}

// ---------------------------------------------------------------------------
// K1: fused MLP 3->64->128 (BN+ReLU each); outputs bf16 SPLIT h2:
// h2h/h2m [b][n][c] row-major. grid 128 x 256; block = (b, 64-point chunk)
// ---------------------------------------------------------------------------
__global__ __launch_bounds__(256) void k1_mlp(
    const float* __restrict__ x,
    const float* __restrict__ w1, const float* __restrict__ g1,
    const float* __restrict__ b1, const float* __restrict__ m1,
    const float* __restrict__ v1,
    const float* __restrict__ w2, const float* __restrict__ g2,
    const float* __restrict__ b2, const float* __restrict__ m2,
    const float* __restrict__ v2,
    unsigned short* __restrict__ h2h, unsigned short* __restrict__ h2m)
{
  __shared__ float w1s[64 * 3];
  __shared__ float s1c[64], o1c[64];
  __shared__ float w2s[64 * 132];   // [o][j], padded stride 132
  __shared__ float s2c[128], o2c[128];
  __shared__ float h1s[64 * 64];    // [o][n]

  const int tid = threadIdx.x;
  const int b = blockIdx.x >> 5;
  const int n0 = (blockIdx.x & 31) << 6;

  if (tid < 64) {
    float s = g1[tid] / sqrtf(v1[tid] + BN_EPS);
    s1c[tid] = s;
    o1c[tid] = b1[tid] - m1[tid] * s;
    w1s[tid * 3 + 0] = w1[tid * 3 + 0];
    w1s[tid * 3 + 1] = w1[tid * 3 + 1];
    w1s[tid * 3 + 2] = w1[tid * 3 + 2];
  }
  if (tid < 128) {
    float s = g2[tid] / sqrtf(v2[tid] + BN_EPS);
    s2c[tid] = s;
    o2c[tid] = b2[tid] - m2[tid] * s;
  }
  for (int it = 0; it < 32; ++it) {
    int idx = tid + (it << 8);          // 8192
    int o = idx & 63, j = idx >> 6;
    w2s[o * 132 + j] = w2[j * 64 + o];  // transpose in LDS
  }
  __syncthreads();

  const int n = tid & 63, half = tid >> 6;

  const float* xp = x + ((size_t)(b << 11) + n0 + n) * 3;
  float xv0 = xp[0], xv1 = xp[1], xv2 = xp[2];
  for (int oo = 0; oo < 16; ++oo) {
    int o = (half << 4) + oo;
    float d = xv0 * w1s[o * 3] + xv1 * w1s[o * 3 + 1] + xv2 * w1s[o * 3 + 2];
    d = d * s1c[o] + o1c[o];
    h1s[o * 64 + n] = fmaxf(d, 0.f);
  }
  __syncthreads();

  float acc[32];
  #pragma unroll
  for (int jj = 0; jj < 32; ++jj) acc[jj] = 0.f;
  const int j0 = half << 5;
  for (int o = 0; o < 64; ++o) {
    float a = h1s[o * 64 + n];
    const f32x4* wrow = (const f32x4*)&w2s[o * 132 + j0];
    #pragma unroll
    for (int jg = 0; jg < 8; ++jg) {
      f32x4 wv = wrow[jg];
      acc[jg * 4 + 0] = fmaf(a, wv[0], acc[jg * 4 + 0]);
      acc[jg * 4 + 1] = fmaf(a, wv[1], acc[jg * 4 + 1]);
      acc[jg * 4 + 2] = fmaf(a, wv[2], acc[jg * 4 + 2]);
      acc[jg * 4 + 3] = fmaf(a, wv[3], acc[jg * 4 + 3]);
    }
  }
  const size_t rowbase = ((size_t)(b << 11) + n0 + n) * 128 + j0;
  #pragma unroll
  for (int q = 0; q < 4; ++q) {
    bf16x8 vh, vm;
    #pragma unroll
    for (int e = 0; e < 8; ++e) {
      int jj = q * 8 + e;
      int j = j0 + jj;
      float vl = fmaxf(acc[jj] * s2c[j] + o2c[j], 0.f);
      float rem;
      unsigned short hh = bf16_hi(vl, rem);
      vh[e] = (short)hh;
      vm[e] = (short)bf16_rne(rem);
    }
    *(bf16x8*)(h2h + rowbase + q * 8) = vh;
    *(bf16x8*)(h2m + rowbase + q * 8) = vm;
  }
}

// ---------------------------------------------------------------------------
// K2: feat[b][k][o] = max_n  h2[b,n,:] . wb[k,o,:]  via bf16 3-pass MFMA
//   (hh + hm + mh; dropped terms ~2^-16 relative, diluted downstream)
// Block = (b, branch) x o-tile 128. W h/m fragments FRAGMENT-LINEAR in LDS
// (wave ds_read_b128 = 1KB contiguous, zero bank conflicts). A-frags straight
// from global (L2-resident). Per wave: 32n x 128o tile, acc f32x4[2][8],
// K=128 in 4 MFMA k-steps, 6 MFMA per 2 LDS reads. No main-loop barriers.
// grid 512 = exactly 2 blocks/CU. LDS 66KB.
// ---------------------------------------------------------------------------
__global__ __launch_bounds__(256, 2) void k2_mfma(
    const unsigned short* __restrict__ h2h,
    const unsigned short* __restrict__ h2m,   // [4][2048][128] bf16
    const unsigned short* __restrict__ wbh,
    const unsigned short* __restrict__ wbm,   // [16][1024][128] bf16
    float* __restrict__ feat)                 // [4][16][1024]
{
  __shared__ unsigned short Wl[2][16384];  // [ver][((ot2*4+ks)*64+lane)*8]
  __shared__ float redm[4][128];

  const int tid = threadIdx.x;
  const int ot = blockIdx.x & 7;
  const int p = blockIdx.x >> 3;
  const int k = p & 15, b = p >> 4;
  const int o0 = ot << 7;

  // stage W fragments: chunk c = ot2*256 + ks*64 + l4*16 + l15 (= dst order)
  {
    const size_t base = ((size_t)(k << 10) + o0) * 128;
    for (int ver = 0; ver < 2; ++ver) {
      const unsigned short* src = (ver ? wbm : wbh) + base;
      for (int it = 0; it < 8; ++it) {
        int c = tid + (it << 8);              // 0..2047
        int l15 = c & 15, l4 = (c >> 4) & 3, ks = (c >> 6) & 3, ot2 = c >> 8;
        int o = (ot2 << 4) + l15, kk = (ks << 5) + (l4 << 3);
        bf16x8 v = *(const bf16x8*)(src + (size_t)o * 128 + kk);
        *(bf16x8*)(&Wl[ver][c << 3]) = v;
      }
    }
  }
  __syncthreads();

  const int lane = tid & 63, w = tid >> 6;
  const int l15 = lane & 15, l4 = lane >> 4;

  const size_t abase = (size_t)b * 2048 * 128 + (size_t)l15 * 128 + l4 * 8;
  const unsigned short* pah = h2h + abase;
  const unsigned short* pam = h2m + abase;

  float mxv[8];
  #pragma unroll
  for (int j = 0; j < 8; ++j) mxv[j] = -3.4e38f;

  for (int itn = 0; itn < 16; ++itn) {
    const int n0 = (itn << 7) + (w << 5);     // wave's 32-row slab
    const unsigned short* ph = pah + (size_t)n0 * 128;
    const unsigned short* pm = pam + (size_t)n0 * 128;

    f32x4 acc[2][8];
    #pragma unroll
    for (int r = 0; r < 2; ++r)
      #pragma unroll
      for (int j = 0; j < 8; ++j) {
        f32x4 z = {0.f, 0.f, 0.f, 0.f};
        acc[r][j] = z;
      }

    #pragma unroll
    for (int ks = 0; ks < 4; ++ks) {
      bf16x8 ah0 = *(const bf16x8*)(ph + (ks << 5));
      bf16x8 ah1 = *(const bf16x8*)(ph + 2048 + (ks << 5));   // +16 rows
      bf16x8 am0 = *(const bf16x8*)(pm + (ks << 5));
      bf16x8 am1 = *(const bf16x8*)(pm + 2048 + (ks << 5));
      #pragma unroll
      for (int ot2 = 0; ot2 < 8; ++ot2) {
        const int cb = (((ot2 << 2) + ks) << 9) + (lane << 3);
        bf16x8 bh = *(const bf16x8*)(&Wl[0][cb]);
        bf16x8 bm = *(const bf16x8*)(&Wl[1][cb]);
        acc[0][ot2] = __builtin_amdgcn_mfma_f32_16x16x32_bf16(ah0, bh, acc[0][ot2], 0, 0, 0);
        acc[1][ot2] = __builtin_amdgcn_mfma_f32_16x16x32_bf16(ah1, bh, acc[1][ot2], 0, 0, 0);
        acc[0][ot2] = __builtin_amdgcn_mfma_f32_16x16x32_bf16(ah0, bm, acc[0][ot2], 0, 0, 0);
        acc[1][ot2] = __builtin_amdgcn_mfma_f32_16x16x32_bf16(ah1, bm, acc[1][ot2], 0, 0, 0);
        acc[0][ot2] = __builtin_amdgcn_mfma_f32_16x16x32_bf16(am0, bh, acc[0][ot2], 0, 0, 0);
        acc[1][ot2] = __builtin_amdgcn_mfma_f32_16x16x32_bf16(am1, bh, acc[1][ot2], 0, 0, 0);
      }
    }
    #pragma unroll
    for (int ot2 = 0; ot2 < 8; ++ot2) {
      #pragma unroll
      for (int r = 0; r < 2; ++r) {
        f32x4 a4 = acc[r][ot2];
        mxv[ot2] = fmaxf(mxv[ot2],
                         fmaxf(fmaxf(a4[0], a4[1]), fmaxf(a4[2], a4[3])));
      }
    }
  }

  // cross-lane: combine l4 groups (C rows) -> per-col max
  #pragma unroll
  for (int ot2 = 0; ot2 < 8; ++ot2) {
    float m = mxv[ot2];
    m = fmaxf(m, __shfl_xor(m, 16));
    m = fmaxf(m, __shfl_xor(m, 32));
    mxv[ot2] = m;
  }
  if (lane < 16) {
    #pragma unroll
    for (int ot2 = 0; ot2 < 8; ++ot2) redm[w][(ot2 << 4) + lane] = mxv[ot2];
  }
  __syncthreads();
  if (tid < 128) {
    float m = fmaxf(fmaxf(redm[0][tid], redm[1][tid]),
                    fmaxf(redm[2][tid], redm[3][tid]));
    feat[((size_t)(b * 16 + k) << 10) + o0 + tid] = m;
  }
}

// ---------------------------------------------------------------------------
// K3a: caps[b][i][e] = squash_e( BN(feat[b][e][i]) ),  e=16. grid 16 x 256
// ---------------------------------------------------------------------------
__global__ __launch_bounds__(256) void k3a_caps(
    const float* __restrict__ feat,
    const float* __restrict__ gb, const float* __restrict__ bb,
    const float* __restrict__ mb, const float* __restrict__ vb,
    float* __restrict__ caps)
{
  int g = blockIdx.x * 256 + threadIdx.x;  // 4096
  int b = g >> 10, i = g & 1023;
  float val[16];
  float ss = 0.f;
  #pragma unroll
  for (int e = 0; e < 16; ++e) {
    int ei = (e << 10) + i;
    float f = feat[((size_t)(b << 4) << 10) + ei];
    float sc = gb[ei] / sqrtf(vb[ei] + BN_EPS);
    float vv = (f - mb[ei]) * sc + bb[ei];
    val[e] = vv;
    ss += vv * vv;
  }
  float nrm = sqrtf(ss);
  float scl = nrm / (1.f + nrm * nrm);
  f32x4* cp = (f32x4*)&caps[(size_t)((b << 10) + i) << 4];
  #pragma unroll
  for (int q = 0; q < 4; ++q) {
    f32x4 v;
    v[0] = val[q * 4 + 0] * scl; v[1] = val[q * 4 + 1] * scl;
    v[2] = val[q * 4 + 2] * scl; v[3] = val[q * 4 + 3] * scl;
    cp[q] = v;
  }
}

// ---------------------------------------------------------------------------
// K3b: u[b][o][i][v] = sum_e caps[b][i][e] * Wc[o][i][e][v]
//      + partial s0 per (o, i-tile). grid 1024 (o=32 x itile=32), 256 thr
// ---------------------------------------------------------------------------
__global__ __launch_bounds__(256) void k3b_u(
    const float* __restrict__ caps, const float* __restrict__ Wc,
    float* __restrict__ u, float* __restrict__ s0p)
{
  __shared__ float caps_l[4 * 32 * 16];  // [b][il][e]
  __shared__ float s_red[16 * 32];       // [w*4+b][v]

  const int tid = threadIdx.x;
  const int o = blockIdx.x & 31, it = blockIdx.x >> 5;
  const int i0 = it << 5;

  for (int ld = 0; ld < 8; ++ld) {
    int idx = tid + (ld << 8);  // 2048 = b*512 + il*16 + e
    int bq = idx >> 9, il = (idx >> 4) & 31, e = idx & 15;
    caps_l[idx] = caps[(size_t)(((bq << 10) + i0 + il) << 4) + e];
  }
  __syncthreads();

  const int w = tid >> 6, lane = tid & 63;
  const int eh = lane >> 5, v = lane & 31;
  float s0acc[4] = {0.f, 0.f, 0.f, 0.f};

  for (int ii = 0; ii < 8; ++ii) {
    int il = (w << 3) + ii;
    int i = i0 + il;
    const float* wc = Wc + ((size_t)(o << 10) + i) * 512 + (eh << 8) + v;
    float acc[4] = {0.f, 0.f, 0.f, 0.f};
    #pragma unroll
    for (int ee = 0; ee < 8; ++ee) {
      float wv = wc[ee * 32];
      int e = (eh << 3) + ee;
      #pragma unroll
      for (int bq = 0; bq < 4; ++bq)
        acc[bq] = fmaf(caps_l[bq * 512 + il * 16 + e], wv, acc[bq]);
    }
    #pragma unroll
    for (int bq = 0; bq < 4; ++bq) {
      acc[bq] += __shfl_xor(acc[bq], 32);
      if (eh == 0) {
        u[(size_t)((((bq << 5) + o) << 10) + i) * 32 + v] = acc[bq];
        s0acc[bq] += acc[bq];
      }
    }
  }
  if (eh == 0) {
    #pragma unroll
    for (int bq = 0; bq < 4; ++bq) s_red[((w << 2) + bq) * 32 + v] = s0acc[bq];
  }
  __syncthreads();
  if (tid < 128) {
    int bq = tid >> 5, vv = tid & 31;
    float s = s_red[bq * 32 + vv] + s_red[(4 + bq) * 32 + vv] +
              s_red[(8 + bq) * 32 + vv] + s_red[(12 + bq) * 32 + vv];
    s0p[(size_t)(((bq << 5) + it) << 5 | o) * 32 + vv] = s;
  }
}

// ---------------------------------------------------------------------------
// K4: out = squash_v( prescale * sum_it spart[b][it][o][v] ). grid 4 x 256
// ---------------------------------------------------------------------------
__global__ __launch_bounds__(256) void k4_squash(
    const float* __restrict__ sp, float* __restrict__ out, float prescale)
{
  const int tid = threadIdx.x;
  const int b = blockIdx.x;
  const int o = tid >> 3, vq = (tid & 7) << 2;
  f32x4 acc = {0.f, 0.f, 0.f, 0.f};
  for (int it = 0; it < 32; ++it) {
    f32x4 p = *(const f32x4*)(sp + (size_t)(((b << 5) + it) << 5 | o) * 32 + vq);
    acc += p;
  }
  acc *= prescale;
  float ss = acc[0] * acc[0] + acc[1] * acc[1] + acc[2] * acc[2] + acc[3] * acc[3];
  ss += __shfl_xor(ss, 1);
  ss += __shfl_xor(ss, 2);
  ss += __shfl_xor(ss, 4);
  float nrm = sqrtf(ss);
  float scl = nrm / (1.f + nrm * nrm);
  f32x4 r = acc * scl;
  *(f32x4*)(out + (size_t)((b << 5) + o) * 32 + vq) = r;
}

// ---------------------------------------------------------------------------
// K5: one routing pass over u. grid 128 (b=4 x itile=32), 256 thr
// ---------------------------------------------------------------------------
__global__ __launch_bounds__(256) void k5_route(
    const float* __restrict__ u, const float* __restrict__ aprev,
    const float* __restrict__ bprev, float* __restrict__ bout,
    float* __restrict__ spart, int pass)
{
  __shared__ float a_l[32 * 33];
  __shared__ float u_l[4 * 32 * 33];
  __shared__ float s_red[4 * 32 * 33];

  const int tid = threadIdx.x;
  const int b = blockIdx.x >> 5, it = blockIdx.x & 31;
  const int i0 = it << 5;

  for (int ld = 0; ld < 4; ++ld) {
    int idx = tid + (ld << 8);  // 1024
    int o = idx >> 5, v = idx & 31;
    a_l[o * 33 + v] = aprev[((b << 5) + o) * 32 + v];
  }
  __syncthreads();

  const int w = tid >> 6, lane = tid & 63;
  const int ln5 = lane & 31, hb = lane >> 5;
  float* uw = &u_l[w * 1056];

  float sacc[16];
  #pragma unroll
  for (int q = 0; q < 16; ++q) sacc[q] = 0.f;

  for (int ii = 0; ii < 8; ++ii) {
    int i = i0 + (w << 3) + ii;
    #pragma unroll
    for (int rr = 0; rr < 16; ++rr) {
      int o = (rr << 1) + hb;
      uw[o * 33 + ln5] = u[(size_t)((((b << 5) + o) << 10) + i) * 32 + ln5];
    }
    float ag = 0.f;
    #pragma unroll
    for (int q = 0; q < 16; ++q) {
      int vv = (hb << 4) + q;
      ag = fmaf(a_l[ln5 * 33 + vv], uw[ln5 * 33 + vv], ag);
    }
    ag += __shfl_xor(ag, 32);
    float bl = ag;
    if (pass == 1) bl += bprev[(((b << 5) + ln5) << 10) + i];
    if (pass == 0 && hb == 0) bout[(((b << 5) + ln5) << 10) + i] = bl;
    float m = bl;
    m = fmaxf(m, __shfl_xor(m, 1));
    m = fmaxf(m, __shfl_xor(m, 2));
    m = fmaxf(m, __shfl_xor(m, 4));
    m = fmaxf(m, __shfl_xor(m, 8));
    m = fmaxf(m, __shfl_xor(m, 16));
    float e = expf(bl - m);
    float sm = e;
    sm += __shfl_xor(sm, 1);
    sm += __shfl_xor(sm, 2);
    sm += __shfl_xor(sm, 4);
    sm += __shfl_xor(sm, 8);
    sm += __shfl_xor(sm, 16);
    float c = e / sm;
    #pragma unroll
    for (int q = 0; q < 16; ++q) {
      int vv = (hb << 4) + q;
      sacc[q] = fmaf(c, uw[ln5 * 33 + vv], sacc[q]);
    }
  }
  #pragma unroll
  for (int q = 0; q < 16; ++q)
    s_red[w * 1056 + ln5 * 33 + (hb << 4) + q] = sacc[q];
  __syncthreads();
  for (int ld = 0; ld < 4; ++ld) {
    int idx = tid + (ld << 8);
    int o = idx >> 5, vv = idx & 31;
    float s = s_red[o * 33 + vv] + s_red[1056 + o * 33 + vv] +
              s_red[2112 + o * 33 + vv] + s_red[3168 + o * 33 + vv];
    spart[(size_t)(((b << 5) + it) << 5 | o) * 32 + vv] = s;
  }
}

// ---------------------------------------------------------------------------
extern "C" void kernel_launch(void* const* d_in, const int* in_sizes, int n_in,
                              void* d_out, int out_size, void* d_ws, size_t ws_size,
                              hipStream_t stream) {
  const float* x  = (const float*)d_in[0];
  const float* w1 = (const float*)d_in[1];
  const float* g1 = (const float*)d_in[2];
  const float* b1 = (const float*)d_in[3];
  const float* m1 = (const float*)d_in[4];
  const float* v1 = (const float*)d_in[5];
  const float* w2 = (const float*)d_in[6];
  const float* g2 = (const float*)d_in[7];
  const float* b2 = (const float*)d_in[8];
  const float* m2 = (const float*)d_in[9];
  const float* v2 = (const float*)d_in[10];
  const float* wb = (const float*)d_in[11];
  const float* gb = (const float*)d_in[12];
  const float* bb = (const float*)d_in[13];
  const float* mb = (const float*)d_in[14];
  const float* vb = (const float*)d_in[15];
  const float* Wc = (const float*)d_in[16];
  float* out = (float*)d_out;
  float* ws = (float*)d_ws;

  // workspace layout (float units). The bf16 split arrays live in the first
  // 4M floats and are DEAD once k2 completes; k3b then writes u over them
  // (stream-ordered, safe). Total 4,857,856 floats = 19.4 MB.
  unsigned short* h2h = (unsigned short*)(ws);              // 1,048,576 u16
  unsigned short* h2m = (unsigned short*)(ws + 524288);     // 1,048,576 u16
  unsigned short* wbh = (unsigned short*)(ws + 1048576);    // 2,097,152 u16
  unsigned short* wbm = (unsigned short*)(ws + 2097152);    // 2,097,152 u16
  float* u    = ws;             // 4*32*1024*32 = 4,194,304 (aliases the above)
  float* feat = ws + 4194304;   // 65536
  float* caps = ws + 4259840;   // 65536
  float* s0p  = ws + 4325376;   // 131072
  float* s1p  = ws + 4456448;   // 131072
  float* s2p  = ws + 4587520;   // 131072
  float* a0   = ws + 4718592;   // 4096
  float* a1   = ws + 4722688;   // 4096
  float* b1l  = ws + 4726784;   // 131072

  k0_wbsplit<<<2048, 256, 0, stream>>>(wb, wbh, wbm);
  k1_mlp<<<128, 256, 0, stream>>>(x, w1, g1, b1, m1, v1,
                                  w2, g2, b2, m2, v2, h2h, h2m);
  k2_mfma<<<512, 256, 0, stream>>>(h2h, h2m, wbh, wbm, feat);
  k3a_caps<<<16, 256, 0, stream>>>(feat, gb, bb, mb, vb, caps);
  k3b_u<<<1024, 256, 0, stream>>>(caps, Wc, u, s0p);
  k4_squash<<<4, 256, 0, stream>>>(s0p, a0, 1.f / 32.f);
  k5_route<<<128, 256, 0, stream>>>(u, a0, b1l, b1l, s1p, 0);
  k4_squash<<<4, 256, 0, stream>>>(s1p, a1, 1.f);
  k5_route<<<128, 256, 0, stream>>>(u, a1, b1l, b1l, s2p, 1);
  k4_squash<<<4, 256, 0, stream>>>(s2p, out, 1.f);
}

// Round 7
// 381.759 us; speedup vs baseline: 2.1072x; 1.0276x over previous
//
#include <hip/hip_runtime.h>
#include <math.h>

typedef float f32x4 __attribute__((ext_vector_type(4)));
typedef short bf16x8 __attribute__((ext_vector_type(8)));

#define BN_EPS 1e-5f

// RNE bf16 split: returns hi bits, rem = v - float(hi)
__device__ __forceinline__ unsigned short bf16_hi(float v, float& rem) {
  unsigned int u = __float_as_uint(v);
  unsigned int r = u + 0x7FFFu + ((u >> 16) & 1u);
  unsigned short h = (unsigned short)(r >> 16);
  rem = v - __uint_as_float((unsigned int)h << 16);
  return h;
}
__device__ __forceinline__ unsigned short bf16_rne(float v) {
  unsigned int u = __float_as_uint(v);
  unsigned int r = u + 0x7FFFu + ((u >> 16) & 1u);
  return (unsigned short)(r >> 16);
}

// ---------------------------------------------------------------------------
// K0: split wb (f32 [16][1024][128]) into bf16 hi/lo arrays.
// grid 2048 x 256, 4 elems/thread
// ---------------------------------------------------------------------------
__global__ __launch_bounds__(256) void k0_wbsplit(
    const float* __restrict__ wb,
    unsigned short* __restrict__ wbh, unsigned short* __restrict__ wbm)
{
  int i = (blockIdx.x * 256 + threadIdx.x) * 4;
  f32x4 v = *(const f32x4*)(wb + i);
  unsigned short h[4], m[4];
  #pragma unroll
  for (int q = 0; q < 4; ++q) {
    float rem;
    h[q] = bf16_hi(v[q], rem);
    m[q] = bf16_rne(rem);
  }
  typedef unsigned short u16x4 __attribute__((ext_vector_type(4)));
  u16x4 vh = {h[0], h[1], h[2], h[3]};
  u16x4 vm = {m[0], m[1], m[2], m[3]};
  *(u16x4*)(wbh + i) = vh;
  *(u16x4*)(wbm + i) = vm;
}

// ---------------------------------------------------------------------------
// K1: fused MLP 3->64->128 (BN+ReLU each); outputs bf16 SPLIT h2:
// h2h/h2m [b][n][c] row-major. grid 128 x 256; block = (b, 64-point chunk)
// ---------------------------------------------------------------------------
__global__ __launch_bounds__(256) void k1_mlp(
    const float* __restrict__ x,
    const float* __restrict__ w1, const float* __restrict__ g1,
    const float* __restrict__ b1, const float* __restrict__ m1,
    const float* __restrict__ v1,
    const float* __restrict__ w2, const float* __restrict__ g2,
    const float* __restrict__ b2, const float* __restrict__ m2,
    const float* __restrict__ v2,
    unsigned short* __restrict__ h2h, unsigned short* __restrict__ h2m)
{
  __shared__ float w1s[64 * 3];
  __shared__ float s1c[64], o1c[64];
  __shared__ float w2s[64 * 132];   // [o][j], padded stride 132
  __shared__ float s2c[128], o2c[128];
  __shared__ float h1s[64 * 64];    // [o][n]

  const int tid = threadIdx.x;
  const int b = blockIdx.x >> 5;
  const int n0 = (blockIdx.x & 31) << 6;

  if (tid < 64) {
    float s = g1[tid] / sqrtf(v1[tid] + BN_EPS);
    s1c[tid] = s;
    o1c[tid] = b1[tid] - m1[tid] * s;
    w1s[tid * 3 + 0] = w1[tid * 3 + 0];
    w1s[tid * 3 + 1] = w1[tid * 3 + 1];
    w1s[tid * 3 + 2] = w1[tid * 3 + 2];
  }
  if (tid < 128) {
    float s = g2[tid] / sqrtf(v2[tid] + BN_EPS);
    s2c[tid] = s;
    o2c[tid] = b2[tid] - m2[tid] * s;
  }
  for (int it = 0; it < 32; ++it) {
    int idx = tid + (it << 8);          // 8192
    int o = idx & 63, j = idx >> 6;
    w2s[o * 132 + j] = w2[j * 64 + o];  // transpose in LDS
  }
  __syncthreads();

  const int n = tid & 63, half = tid >> 6;

  const float* xp = x + ((size_t)(b << 11) + n0 + n) * 3;
  float xv0 = xp[0], xv1 = xp[1], xv2 = xp[2];
  for (int oo = 0; oo < 16; ++oo) {
    int o = (half << 4) + oo;
    float d = xv0 * w1s[o * 3] + xv1 * w1s[o * 3 + 1] + xv2 * w1s[o * 3 + 2];
    d = d * s1c[o] + o1c[o];
    h1s[o * 64 + n] = fmaxf(d, 0.f);
  }
  __syncthreads();

  float acc[32];
  #pragma unroll
  for (int jj = 0; jj < 32; ++jj) acc[jj] = 0.f;
  const int j0 = half << 5;
  for (int o = 0; o < 64; ++o) {
    float a = h1s[o * 64 + n];
    const f32x4* wrow = (const f32x4*)&w2s[o * 132 + j0];
    #pragma unroll
    for (int jg = 0; jg < 8; ++jg) {
      f32x4 wv = wrow[jg];
      acc[jg * 4 + 0] = fmaf(a, wv[0], acc[jg * 4 + 0]);
      acc[jg * 4 + 1] = fmaf(a, wv[1], acc[jg * 4 + 1]);
      acc[jg * 4 + 2] = fmaf(a, wv[2], acc[jg * 4 + 2]);
      acc[jg * 4 + 3] = fmaf(a, wv[3], acc[jg * 4 + 3]);
    }
  }
  const size_t rowbase = ((size_t)(b << 11) + n0 + n) * 128 + j0;
  #pragma unroll
  for (int q = 0; q < 4; ++q) {
    bf16x8 vh, vm;
    #pragma unroll
    for (int e = 0; e < 8; ++e) {
      int jj = q * 8 + e;
      int j = j0 + jj;
      float vl = fmaxf(acc[jj] * s2c[j] + o2c[j], 0.f);
      float rem;
      unsigned short hh = bf16_hi(vl, rem);
      vh[e] = (short)hh;
      vm[e] = (short)bf16_rne(rem);
    }
    *(bf16x8*)(h2h + rowbase + q * 8) = vh;
    *(bf16x8*)(h2m + rowbase + q * 8) = vm;
  }
}

// ---------------------------------------------------------------------------
// K2: feat[b][k][o] = max_n  h2[b,n,:] . wb[k,o,:]  via bf16 3-pass MFMA.
// XCD-aware decode: b = xcd>>1 so each XCD's L2 caches ONE h2 b-slice (2MB).
// W fragments LDS-resident (fragment-linear, conflict-free); A-frags from
// global (L2-hit after swizzle) with explicit depth-1 ping-pong prefetch.
// grid 512 = 2 blocks/CU, 256 thr. LDS 66KB.
// ---------------------------------------------------------------------------
__global__ __launch_bounds__(256, 2) void k2_mfma(
    const unsigned short* __restrict__ h2h,
    const unsigned short* __restrict__ h2m,   // [4][2048][128] bf16
    const unsigned short* __restrict__ wbh,
    const unsigned short* __restrict__ wbm,   // [16][1024][128] bf16
    float* __restrict__ feat)                 // [4][16][1024]
{
  __shared__ unsigned short Wl[2][16384];  // [ver][((ot2*4+ks)*64+lane)*8]
  __shared__ float redm[4][128];

  const int tid = threadIdx.x;
  const int bid = blockIdx.x;
  const int xcd = bid & 7;                  // HW round-robin heuristic
  const int rest = bid >> 3;                // 0..63
  const int b = xcd >> 1;                   // one b-slice per XCD pair-slot
  const int k = rest & 15;
  const int ot = ((xcd & 1) << 2) + (rest >> 4);
  const int o0 = ot << 7;

  // stage W fragments: chunk c = ot2*256 + ks*64 + l4*16 + l15 (= dst order)
  {
    const size_t base = ((size_t)(k << 10) + o0) * 128;
    for (int ver = 0; ver < 2; ++ver) {
      const unsigned short* src = (ver ? wbm : wbh) + base;
      for (int it = 0; it < 8; ++it) {
        int c = tid + (it << 8);              // 0..2047
        int l15 = c & 15, l4 = (c >> 4) & 3, ks = (c >> 6) & 3, ot2 = c >> 8;
        int o = (ot2 << 4) + l15, kk = (ks << 5) + (l4 << 3);
        bf16x8 v = *(const bf16x8*)(src + (size_t)o * 128 + kk);
        *(bf16x8*)(&Wl[ver][c << 3]) = v;
      }
    }
  }
  __syncthreads();

  const int lane = tid & 63, w = tid >> 6;
  const int l15 = lane & 15, l4 = lane >> 4;

  const size_t abase = (size_t)b * 2048 * 128 + (size_t)l15 * 128 + l4 * 8;
  const unsigned short* pah = h2h + abase;
  const unsigned short* pam = h2m + abase;

  float mxv[8];
  #pragma unroll
  for (int j = 0; j < 8; ++j) mxv[j] = -3.4e38f;

  // ping-pong A-frag buffers: [0]=ah0 [1]=ah1(+16 rows) [2]=am0 [3]=am1
  bf16x8 f0[4], f1[4];
  {
    const size_t so = (size_t)(w << 5) * 128;
    f0[0] = *(const bf16x8*)(pah + so);
    f0[1] = *(const bf16x8*)(pah + so + 2048);
    f0[2] = *(const bf16x8*)(pam + so);
    f0[3] = *(const bf16x8*)(pam + so + 2048);
  }

  for (int itn = 0; itn < 16; ++itn) {
    const size_t so = ((size_t)(itn << 7) + (w << 5)) * 128;
    const size_t sn = (itn < 15) ? so + 128 * 128 : so;  // next slab (wrap-safe)

    f32x4 acc[2][8];
    #pragma unroll
    for (int r = 0; r < 2; ++r)
      #pragma unroll
      for (int j = 0; j < 8; ++j) {
        f32x4 z = {0.f, 0.f, 0.f, 0.f};
        acc[r][j] = z;
      }

    #pragma unroll
    for (int kp = 0; kp < 2; ++kp) {
      const int ksA = kp << 1, ksB = ksA + 1;
      // prefetch ksB -> f1 (issues before the 48 MFMAs below)
      {
        const size_t sp = so + (ksB << 5);
        f1[0] = *(const bf16x8*)(pah + sp);
        f1[1] = *(const bf16x8*)(pah + sp + 2048);
        f1[2] = *(const bf16x8*)(pam + sp);
        f1[3] = *(const bf16x8*)(pam + sp + 2048);
      }
      #pragma unroll
      for (int ot2 = 0; ot2 < 8; ++ot2) {
        const int cb = (((ot2 << 2) + ksA) << 9) + (lane << 3);
        bf16x8 bh = *(const bf16x8*)(&Wl[0][cb]);
        bf16x8 bm = *(const bf16x8*)(&Wl[1][cb]);
        acc[0][ot2] = __builtin_amdgcn_mfma_f32_16x16x32_bf16(f0[0], bh, acc[0][ot2], 0, 0, 0);
        acc[1][ot2] = __builtin_amdgcn_mfma_f32_16x16x32_bf16(f0[1], bh, acc[1][ot2], 0, 0, 0);
        acc[0][ot2] = __builtin_amdgcn_mfma_f32_16x16x32_bf16(f0[0], bm, acc[0][ot2], 0, 0, 0);
        acc[1][ot2] = __builtin_amdgcn_mfma_f32_16x16x32_bf16(f0[1], bm, acc[1][ot2], 0, 0, 0);
        acc[0][ot2] = __builtin_amdgcn_mfma_f32_16x16x32_bf16(f0[2], bh, acc[0][ot2], 0, 0, 0);
        acc[1][ot2] = __builtin_amdgcn_mfma_f32_16x16x32_bf16(f0[3], bh, acc[1][ot2], 0, 0, 0);
      }
      // prefetch (kp==0: ks=2) / (kp==1: next slab ks=0) -> f0
      {
        const size_t sp = (kp == 0) ? (so + 64) : sn;
        f0[0] = *(const bf16x8*)(pah + sp);
        f0[1] = *(const bf16x8*)(pah + sp + 2048);
        f0[2] = *(const bf16x8*)(pam + sp);
        f0[3] = *(const bf16x8*)(pam + sp + 2048);
      }
      #pragma unroll
      for (int ot2 = 0; ot2 < 8; ++ot2) {
        const int cb = (((ot2 << 2) + ksB) << 9) + (lane << 3);
        bf16x8 bh = *(const bf16x8*)(&Wl[0][cb]);
        bf16x8 bm = *(const bf16x8*)(&Wl[1][cb]);
        acc[0][ot2] = __builtin_amdgcn_mfma_f32_16x16x32_bf16(f1[0], bh, acc[0][ot2], 0, 0, 0);
        acc[1][ot2] = __builtin_amdgcn_mfma_f32_16x16x32_bf16(f1[1], bh, acc[1][ot2], 0, 0, 0);
        acc[0][ot2] = __builtin_amdgcn_mfma_f32_16x16x32_bf16(f1[0], bm, acc[0][ot2], 0, 0, 0);
        acc[1][ot2] = __builtin_amdgcn_mfma_f32_16x16x32_bf16(f1[1], bm, acc[1][ot2], 0, 0, 0);
        acc[0][ot2] = __builtin_amdgcn_mfma_f32_16x16x32_bf16(f1[2], bh, acc[0][ot2], 0, 0, 0);
        acc[1][ot2] = __builtin_amdgcn_mfma_f32_16x16x32_bf16(f1[3], bh, acc[1][ot2], 0, 0, 0);
      }
    }

    #pragma unroll
    for (int ot2 = 0; ot2 < 8; ++ot2) {
      #pragma unroll
      for (int r = 0; r < 2; ++r) {
        f32x4 a4 = acc[r][ot2];
        mxv[ot2] = fmaxf(mxv[ot2],
                         fmaxf(fmaxf(a4[0], a4[1]), fmaxf(a4[2], a4[3])));
      }
    }
  }

  // cross-lane: combine l4 groups (C rows) -> per-col max
  #pragma unroll
  for (int ot2 = 0; ot2 < 8; ++ot2) {
    float m = mxv[ot2];
    m = fmaxf(m, __shfl_xor(m, 16));
    m = fmaxf(m, __shfl_xor(m, 32));
    mxv[ot2] = m;
  }
  if (lane < 16) {
    #pragma unroll
    for (int ot2 = 0; ot2 < 8; ++ot2) redm[w][(ot2 << 4) + lane] = mxv[ot2];
  }
  __syncthreads();
  if (tid < 128) {
    float m = fmaxf(fmaxf(redm[0][tid], redm[1][tid]),
                    fmaxf(redm[2][tid], redm[3][tid]));
    feat[((size_t)(b * 16 + k) << 10) + o0 + tid] = m;
  }
}

// ---------------------------------------------------------------------------
// K3a: caps[b][i][e] = squash_e( BN(feat[b][e][i]) ),  e=16. grid 16 x 256
// ---------------------------------------------------------------------------
__global__ __launch_bounds__(256) void k3a_caps(
    const float* __restrict__ feat,
    const float* __restrict__ gb, const float* __restrict__ bb,
    const float* __restrict__ mb, const float* __restrict__ vb,
    float* __restrict__ caps)
{
  int g = blockIdx.x * 256 + threadIdx.x;  // 4096
  int b = g >> 10, i = g & 1023;
  float val[16];
  float ss = 0.f;
  #pragma unroll
  for (int e = 0; e < 16; ++e) {
    int ei = (e << 10) + i;
    float f = feat[((size_t)(b << 4) << 10) + ei];
    float sc = gb[ei] / sqrtf(vb[ei] + BN_EPS);
    float vv = (f - mb[ei]) * sc + bb[ei];
    val[e] = vv;
    ss += vv * vv;
  }
  float nrm = sqrtf(ss);
  float scl = nrm / (1.f + nrm * nrm);
  f32x4* cp = (f32x4*)&caps[(size_t)((b << 10) + i) << 4];
  #pragma unroll
  for (int q = 0; q < 4; ++q) {
    f32x4 v;
    v[0] = val[q * 4 + 0] * scl; v[1] = val[q * 4 + 1] * scl;
    v[2] = val[q * 4 + 2] * scl; v[3] = val[q * 4 + 3] * scl;
    cp[q] = v;
  }
}

// ---------------------------------------------------------------------------
// K3b: u[b][o][i][v] = sum_e caps[b][i][e] * Wc[o][i][e][v]
//      + partial s0 per (o, i-tile). grid 1024 (o=32 x itile=32), 256 thr
// ---------------------------------------------------------------------------
__global__ __launch_bounds__(256) void k3b_u(
    const float* __restrict__ caps, const float* __restrict__ Wc,
    float* __restrict__ u, float* __restrict__ s0p)
{
  __shared__ float caps_l[4 * 32 * 16];  // [b][il][e]
  __shared__ float s_red[16 * 32];       // [w*4+b][v]

  const int tid = threadIdx.x;
  const int o = blockIdx.x & 31, it = blockIdx.x >> 5;
  const int i0 = it << 5;

  for (int ld = 0; ld < 8; ++ld) {
    int idx = tid + (ld << 8);  // 2048 = b*512 + il*16 + e
    int bq = idx >> 9, il = (idx >> 4) & 31, e = idx & 15;
    caps_l[idx] = caps[(size_t)(((bq << 10) + i0 + il) << 4) + e];
  }
  __syncthreads();

  const int w = tid >> 6, lane = tid & 63;
  const int eh = lane >> 5, v = lane & 31;
  float s0acc[4] = {0.f, 0.f, 0.f, 0.f};

  for (int ii = 0; ii < 8; ++ii) {
    int il = (w << 3) + ii;
    int i = i0 + il;
    const float* wc = Wc + ((size_t)(o << 10) + i) * 512 + (eh << 8) + v;
    float acc[4] = {0.f, 0.f, 0.f, 0.f};
    #pragma unroll
    for (int ee = 0; ee < 8; ++ee) {
      float wv = wc[ee * 32];
      int e = (eh << 3) + ee;
      #pragma unroll
      for (int bq = 0; bq < 4; ++bq)
        acc[bq] = fmaf(caps_l[bq * 512 + il * 16 + e], wv, acc[bq]);
    }
    #pragma unroll
    for (int bq = 0; bq < 4; ++bq) {
      acc[bq] += __shfl_xor(acc[bq], 32);
      if (eh == 0) {
        u[(size_t)((((bq << 5) + o) << 10) + i) * 32 + v] = acc[bq];
        s0acc[bq] += acc[bq];
      }
    }
  }
  if (eh == 0) {
    #pragma unroll
    for (int bq = 0; bq < 4; ++bq) s_red[((w << 2) + bq) * 32 + v] = s0acc[bq];
  }
  __syncthreads();
  if (tid < 128) {
    int bq = tid >> 5, vv = tid & 31;
    float s = s_red[bq * 32 + vv] + s_red[(4 + bq) * 32 + vv] +
              s_red[(8 + bq) * 32 + vv] + s_red[(12 + bq) * 32 + vv];
    s0p[(size_t)(((bq << 5) + it) << 5 | o) * 32 + vv] = s;
  }
}

// ---------------------------------------------------------------------------
// K4: out = squash_v( prescale * sum_it spart[b][it][o][v] ). grid 4 x 256
// ---------------------------------------------------------------------------
__global__ __launch_bounds__(256) void k4_squash(
    const float* __restrict__ sp, float* __restrict__ out, float prescale)
{
  const int tid = threadIdx.x;
  const int b = blockIdx.x;
  const int o = tid >> 3, vq = (tid & 7) << 2;
  f32x4 acc = {0.f, 0.f, 0.f, 0.f};
  for (int it = 0; it < 32; ++it) {
    f32x4 p = *(const f32x4*)(sp + (size_t)(((b << 5) + it) << 5 | o) * 32 + vq);
    acc += p;
  }
  acc *= prescale;
  float ss = acc[0] * acc[0] + acc[1] * acc[1] + acc[2] * acc[2] + acc[3] * acc[3];
  ss += __shfl_xor(ss, 1);
  ss += __shfl_xor(ss, 2);
  ss += __shfl_xor(ss, 4);
  float nrm = sqrtf(ss);
  float scl = nrm / (1.f + nrm * nrm);
  f32x4 r = acc * scl;
  *(f32x4*)(out + (size_t)((b << 5) + o) * 32 + vq) = r;
}

// ---------------------------------------------------------------------------
// K5: one routing pass over u. grid 128 (b=4 x itile=32), 256 thr
// ---------------------------------------------------------------------------
__global__ __launch_bounds__(256) void k5_route(
    const float* __restrict__ u, const float* __restrict__ aprev,
    const float* __restrict__ bprev, float* __restrict__ bout,
    float* __restrict__ spart, int pass)
{
  __shared__ float a_l[32 * 33];
  __shared__ float u_l[4 * 32 * 33];
  __shared__ float s_red[4 * 32 * 33];

  const int tid = threadIdx.x;
  const int b = blockIdx.x >> 5, it = blockIdx.x & 31;
  const int i0 = it << 5;

  for (int ld = 0; ld < 4; ++ld) {
    int idx = tid + (ld << 8);  // 1024
    int o = idx >> 5, v = idx & 31;
    a_l[o * 33 + v] = aprev[((b << 5) + o) * 32 + v];
  }
  __syncthreads();

  const int w = tid >> 6, lane = tid & 63;
  const int ln5 = lane & 31, hb = lane >> 5;
  float* uw = &u_l[w * 1056];

  float sacc[16];
  #pragma unroll
  for (int q = 0; q < 16; ++q) sacc[q] = 0.f;

  for (int ii = 0; ii < 8; ++ii) {
    int i = i0 + (w << 3) + ii;
    #pragma unroll
    for (int rr = 0; rr < 16; ++rr) {
      int o = (rr << 1) + hb;
      uw[o * 33 + ln5] = u[(size_t)((((b << 5) + o) << 10) + i) * 32 + ln5];
    }
    float ag = 0.f;
    #pragma unroll
    for (int q = 0; q < 16; ++q) {
      int vv = (hb << 4) + q;
      ag = fmaf(a_l[ln5 * 33 + vv], uw[ln5 * 33 + vv], ag);
    }
    ag += __shfl_xor(ag, 32);
    float bl = ag;
    if (pass == 1) bl += bprev[(((b << 5) + ln5) << 10) + i];
    if (pass == 0 && hb == 0) bout[(((b << 5) + ln5) << 10) + i] = bl;
    float m = bl;
    m = fmaxf(m, __shfl_xor(m, 1));
    m = fmaxf(m, __shfl_xor(m, 2));
    m = fmaxf(m, __shfl_xor(m, 4));
    m = fmaxf(m, __shfl_xor(m, 8));
    m = fmaxf(m, __shfl_xor(m, 16));
    float e = expf(bl - m);
    float sm = e;
    sm += __shfl_xor(sm, 1);
    sm += __shfl_xor(sm, 2);
    sm += __shfl_xor(sm, 4);
    sm += __shfl_xor(sm, 8);
    sm += __shfl_xor(sm, 16);
    float c = e / sm;
    #pragma unroll
    for (int q = 0; q < 16; ++q) {
      int vv = (hb << 4) + q;
      sacc[q] = fmaf(c, uw[ln5 * 33 + vv], sacc[q]);
    }
  }
  #pragma unroll
  for (int q = 0; q < 16; ++q)
    s_red[w * 1056 + ln5 * 33 + (hb << 4) + q] = sacc[q];
  __syncthreads();
  for (int ld = 0; ld < 4; ++ld) {
    int idx = tid + (ld << 8);
    int o = idx >> 5, vv = idx & 31;
    float s = s_red[o * 33 + vv] + s_red[1056 + o * 33 + vv] +
              s_red[2112 + o * 33 + vv] + s_red[3168 + o * 33 + vv];
    spart[(size_t)(((b << 5) + it) << 5 | o) * 32 + vv] = s;
  }
}

// ---------------------------------------------------------------------------
extern "C" void kernel_launch(void* const* d_in, const int* in_sizes, int n_in,
                              void* d_out, int out_size, void* d_ws, size_t ws_size,
                              hipStream_t stream) {
  const float* x  = (const float*)d_in[0];
  const float* w1 = (const float*)d_in[1];
  const float* g1 = (const float*)d_in[2];
  const float* b1 = (const float*)d_in[3];
  const float* m1 = (const float*)d_in[4];
  const float* v1 = (const float*)d_in[5];
  const float* w2 = (const float*)d_in[6];
  const float* g2 = (const float*)d_in[7];
  const float* b2 = (const float*)d_in[8];
  const float* m2 = (const float*)d_in[9];
  const float* v2 = (const float*)d_in[10];
  const float* wb = (const float*)d_in[11];
  const float* gb = (const float*)d_in[12];
  const float* bb = (const float*)d_in[13];
  const float* mb = (const float*)d_in[14];
  const float* vb = (const float*)d_in[15];
  const float* Wc = (const float*)d_in[16];
  float* out = (float*)d_out;
  float* ws = (float*)d_ws;

  // workspace layout (float units). The bf16 split arrays live in the first
  // 4M floats and are DEAD once k2 completes; k3b then writes u over them
  // (stream-ordered, safe). Total 4,857,856 floats = 19.4 MB.
  unsigned short* h2h = (unsigned short*)(ws);              // 1,048,576 u16
  unsigned short* h2m = (unsigned short*)(ws + 524288);     // 1,048,576 u16
  unsigned short* wbh = (unsigned short*)(ws + 1048576);    // 2,097,152 u16
  unsigned short* wbm = (unsigned short*)(ws + 2097152);    // 2,097,152 u16
  float* u    = ws;             // 4*32*1024*32 = 4,194,304 (aliases the above)
  float* feat = ws + 4194304;   // 65536
  float* caps = ws + 4259840;   // 65536
  float* s0p  = ws + 4325376;   // 131072
  float* s1p  = ws + 4456448;   // 131072
  float* s2p  = ws + 4587520;   // 131072
  float* a0   = ws + 4718592;   // 4096
  float* a1   = ws + 4722688;   // 4096
  float* b1l  = ws + 4726784;   // 131072

  k0_wbsplit<<<2048, 256, 0, stream>>>(wb, wbh, wbm);
  k1_mlp<<<128, 256, 0, stream>>>(x, w1, g1, b1, m1, v1,
                                  w2, g2, b2, m2, v2, h2h, h2m);
  k2_mfma<<<512, 256, 0, stream>>>(h2h, h2m, wbh, wbm, feat);
  k3a_caps<<<16, 256, 0, stream>>>(feat, gb, bb, mb, vb, caps);
  k3b_u<<<1024, 256, 0, stream>>>(caps, Wc, u, s0p);
  k4_squash<<<4, 256, 0, stream>>>(s0p, a0, 1.f / 32.f);
  k5_route<<<128, 256, 0, stream>>>(u, a0, b1l, b1l, s1p, 0);
  k4_squash<<<4, 256, 0, stream>>>(s1p, a1, 1.f);
  k5_route<<<128, 256, 0, stream>>>(u, a1, b1l, b1l, s2p, 1);
  k4_squash<<<4, 256, 0, stream>>>(s2p, out, 1.f);
}